// Round 11
// baseline (677.555 us; speedup 1.0000x reference)
//
#include <hip/hip_runtime.h>
#include <hip/hip_bf16.h>

constexpr int N_USER = 100000;
constexpr int N_ITEM = 200000;
constexpr int N_ALL  = N_USER + N_ITEM;
constexpr int E_UI   = 3200000;
constexpr int E_UU   = 1600000;
constexpr int D      = 64;
constexpr int BLK    = 256;

// bucketing: 2048 rows per bucket (nb_UI = 147) -> per-block per-bucket scatter
// payload ~full cache lines (no write amplification)
constexpr int RPB_SHIFT = 11;
constexpr int RPB       = 1 << RPB_SHIFT;   // 2048
constexpr int MAX_NB    = 160;              // >= cdiv(N_ALL, RPB) = 147
constexpr int SRC_BITS  = 19;               // N_ALL < 2^19
constexpr int SRC_MASK  = (1 << SRC_BITS) - 1;

// bin_scatter tile geometry
constexpr int SBLK = 512;
constexpr int EPT  = 16;
constexpr int TILE = SBLK * EPT;            // 8192 edges per block

typedef __hip_bfloat16 bf16;
typedef float f32x4 __attribute__((ext_vector_type(4)));
typedef int   i32x4 __attribute__((ext_vector_type(4)));

// ---------------- small helpers ----------------

__device__ inline int wave_incl_scan(int x, int lane) {
    #pragma unroll
    for (int off = 1; off < 64; off <<= 1) {
        int y = __shfl_up(x, off, 64);
        if (lane >= off) x += y;
    }
    return x;
}

static inline int cdiv(int a, int b) { return (a + b - 1) / b; }

// accumulate 8 bf16 (packed in an int4) into 8 f32 accumulators
__device__ inline void acc8(float* acc, const int4 v) {
    acc[0] += __int_as_float(v.x << 16);
    acc[1] += __int_as_float(v.x & 0xffff0000);
    acc[2] += __int_as_float(v.y << 16);
    acc[3] += __int_as_float(v.y & 0xffff0000);
    acc[4] += __int_as_float(v.z << 16);
    acc[5] += __int_as_float(v.z & 0xffff0000);
    acc[6] += __int_as_float(v.w << 16);
    acc[7] += __int_as_float(v.w & 0xffff0000);
}

// ---------------- init kernels (scaled bf16 emb only; sums fused into layer 1) ----------------

__global__ void init_ui_kernel(const float* __restrict__ ue,
                               const float* __restrict__ ie,
                               const float* __restrict__ rsq_out,
                               bf16* __restrict__ emb_scaled) {
    size_t t = (size_t)blockIdx.x * blockDim.x + threadIdx.x;
    const size_t total = (size_t)N_ALL * D;
    if (t >= total) return;
    const size_t userN = (size_t)N_USER * D;
    float v = (t < userN) ? ue[t] : ie[t - userN];
    int row = (int)(t >> 6);
    emb_scaled[t] = __float2bfloat16(v * rsq_out[row]);
}

__global__ void init_uu_kernel(const float* __restrict__ ue,
                               const float* __restrict__ rsq_out,
                               bf16* __restrict__ emb_scaled) {
    size_t t = (size_t)blockIdx.x * blockDim.x + threadIdx.x;
    const size_t total = (size_t)N_USER * D;
    if (t >= total) return;
    float v = ue[t];
    int row = (int)(t >> 6);
    emb_scaled[t] = __float2bfloat16(v * rsq_out[row]);
}

// ---------------- bucket histograms (both sides in one pass) ----------------

__global__ void bucket_hist2_kernel(const int* __restrict__ dst,
                                    const int* __restrict__ src, int E, int nb,
                                    int* __restrict__ bcntD_g,
                                    int* __restrict__ bcntS_g) {
    __shared__ int cD[MAX_NB];
    __shared__ int cS[MAX_NB];
    for (int b = threadIdx.x; b < nb; b += blockDim.x) { cD[b] = 0; cS[b] = 0; }
    __syncthreads();
    for (int e = blockIdx.x * blockDim.x + threadIdx.x; e < E;
         e += gridDim.x * blockDim.x) {
        atomicAdd(&cD[dst[e] >> RPB_SHIFT], 1);
        atomicAdd(&cS[src[e] >> RPB_SHIFT], 1);
    }
    __syncthreads();
    for (int b = threadIdx.x; b < nb; b += blockDim.x) {
        if (cD[b]) atomicAdd(&bcntD_g[b], cD[b]);
        if (cS[b]) atomicAdd(&bcntS_g[b], cS[b]);
    }
}

// ---------------- single-block exclusive scans (dst + src in one launch) ----------------

__device__ void scan_one(const int* __restrict__ cnt, int nb,
                         int* __restrict__ base, int* __restrict__ cursor,
                         int* wsum, int* carry_s) {
    int t = threadIdx.x, lane = t & 63, wid = t >> 6;
    if (t == 0) *carry_s = 0;
    for (int b0 = 0; b0 < nb; b0 += BLK) {
        __syncthreads();
        int i = b0 + t;
        int x = (i < nb) ? cnt[i] : 0;
        int s = wave_incl_scan(x, lane);
        if (lane == 63) wsum[wid] = s;
        __syncthreads();
        int add = *carry_s;
        for (int w = 0; w < wid; ++w) add += wsum[w];
        int excl = add + s - x;
        if (i < nb) { base[i] = excl; cursor[i] = excl; }
        int total = wsum[0] + wsum[1] + wsum[2] + wsum[3];
        __syncthreads();
        if (t == 0) *carry_s = add + total;  // add == old carry for t0
    }
    __syncthreads();
    if (t == 0) base[nb] = *carry_s;
    __syncthreads();
}

__global__ void scan2_buckets_kernel(const int* __restrict__ cntD, int nb,
                                     int* __restrict__ baseD, int* __restrict__ curD,
                                     const int* __restrict__ cntS,
                                     int* __restrict__ baseS, int* __restrict__ curS) {
    __shared__ int wsum[4];
    __shared__ int carry_s;
    scan_one(cntD, nb, baseD, curD, wsum, &carry_s);
    scan_one(cntS, nb, baseS, curS, wsum, &carry_s);
}

// ---------------- bin scatter: src IDs -> bucket-contiguous ----------------

__global__ __launch_bounds__(SBLK) void bin_scatter_src_kernel(
    const int* __restrict__ src, int E, int nb,
    int* __restrict__ cursor, int* __restrict__ binned_src) {
    __shared__ int bcnt[MAX_NB];
    __shared__ int bbase[MAX_NB];
    int t = threadIdx.x;
    for (int b = t; b < nb; b += SBLK) bcnt[b] = 0;
    __syncthreads();
    int base_e = blockIdx.x * TILE;
    int myk[EPT], myr[EPT];
    #pragma unroll
    for (int j = 0; j < EPT; ++j) {
        int e = base_e + j * SBLK + t;
        if (e < E) {
            int s = src[e];
            myk[j] = s;
            myr[j] = atomicAdd(&bcnt[s >> RPB_SHIFT], 1);
        } else {
            myk[j] = -1;
        }
    }
    __syncthreads();
    for (int b = t; b < nb; b += SBLK)
        if (bcnt[b] > 0) bbase[b] = atomicAdd(&cursor[b], bcnt[b]);
    __syncthreads();
    #pragma unroll
    for (int j = 0; j < EPT; ++j) {
        if (myk[j] >= 0)
            binned_src[bbase[myk[j] >> RPB_SHIFT] + myr[j]] = myk[j];
    }
}

// ---------------- bin scatter: edges -> bucket-contiguous packed (dstLocal<<19|src) ----------------

__global__ __launch_bounds__(SBLK) void bin_scatter_kernel(
    const int* __restrict__ src, const int* __restrict__ dst, int E, int nb,
    int* __restrict__ cursor, int* __restrict__ binned) {
    __shared__ int bcnt[MAX_NB];
    __shared__ int bbase[MAX_NB];
    int t = threadIdx.x;
    for (int b = t; b < nb; b += SBLK) bcnt[b] = 0;
    __syncthreads();
    int base_e = blockIdx.x * TILE;
    int myp[EPT], myb[EPT], myr[EPT];
    #pragma unroll
    for (int j = 0; j < EPT; ++j) {
        int e = base_e + j * SBLK + t;
        if (e < E) {
            int d = dst[e];
            int s = src[e];
            int b = d >> RPB_SHIFT;
            myp[j] = ((d & (RPB - 1)) << SRC_BITS) | s;
            myb[j] = b;
            myr[j] = atomicAdd(&bcnt[b], 1);
        } else {
            myb[j] = -1;
        }
    }
    __syncthreads();
    for (int b = t; b < nb; b += SBLK)
        if (bcnt[b] > 0) bbase[b] = atomicAdd(&cursor[b], bcnt[b]);
    __syncthreads();
    #pragma unroll
    for (int j = 0; j < EPT; ++j) {
        if (myb[j] >= 0)
            binned[bbase[myb[j]] + myr[j]] = myp[j];
    }
}

// ---------------- merged per-bucket finalize ----------------
// blocks [0, nb): dst-side CSR (row_ptr, rsq_in, col) from packed binned
// blocks [nb, 2nb): src-side degree -> rsq_out

__global__ void bucket_finalize_kernel(const int* __restrict__ binned,
                                       const int* __restrict__ baseD,
                                       const int* __restrict__ binned_src,
                                       const int* __restrict__ baseS,
                                       int nb, int n,
                                       int* __restrict__ row_ptr,
                                       float* __restrict__ rsq_in,
                                       int* __restrict__ col,
                                       float* __restrict__ rsq_out) {
    __shared__ int deg[RPB];
    __shared__ int cur[RPB];
    __shared__ int wsum[4];
    __shared__ int carry;
    int bb = blockIdx.x;
    int t = threadIdx.x, lane = t & 63, wid = t >> 6;

    if (bb >= nb) {
        // ---- src side: out-degree -> rsq_out ----
        int b = bb - nb;
        int row0 = b << RPB_SHIFT;
        for (int i = t; i < RPB; i += BLK) deg[i] = 0;
        __syncthreads();
        int beg = baseS[b], end = baseS[b + 1];
        for (int e = beg + t; e < end; e += BLK)
            atomicAdd(&deg[binned_src[e] - row0], 1);
        __syncthreads();
        for (int i = t; i < RPB; i += BLK)
            if (row0 + i < n)
                rsq_out[row0 + i] = 1.0f / sqrtf(fmaxf((float)deg[i], 1.0f));
        return;
    }

    // ---- dst side: CSR ----
    int b = bb;
    int row0 = b << RPB_SHIFT;
    int nrows = min(RPB, n - row0);
    int beg = baseD[b], end = baseD[b + 1];

    for (int i = t; i < RPB; i += BLK) deg[i] = 0;
    __syncthreads();

    for (int e = beg + t; e < end; e += BLK)
        atomicAdd(&deg[binned[e] >> SRC_BITS], 1);

    // chunked exclusive scan of deg[0..RPB) -> cur (absolute), row_ptr, rsq_in
    if (t == 0) carry = 0;
    for (int c0 = 0; c0 < RPB; c0 += BLK) {
        __syncthreads();
        int x = deg[c0 + t];
        int s = wave_incl_scan(x, lane);
        if (lane == 63) wsum[wid] = s;
        __syncthreads();
        int add = carry;
        for (int w = 0; w < wid; ++w) add += wsum[w];
        int excl = add + s - x;
        cur[c0 + t] = beg + excl;
        if (c0 + t < nrows) {
            row_ptr[row0 + c0 + t] = beg + excl;
            rsq_in[row0 + c0 + t] = 1.0f / sqrtf(fmaxf((float)x, 1.0f));
        }
        int total = wsum[0] + wsum[1] + wsum[2] + wsum[3];
        __syncthreads();
        if (t == 0) carry = add + total;  // add == old carry for t0
    }
    __syncthreads();
    if (b == nb - 1 && t == 0) row_ptr[n] = end;
    __syncthreads();

    for (int e = beg + t; e < end; e += BLK) {
        int p = binned[e];
        int pos = atomicAdd(&cur[p >> SRC_BITS], 1);
        col[pos] = p & SRC_MASK;
    }
}

// ---------------- fused GCN layer: 8 rows/wave, 8 lanes/row ----------------
// Hoisted epilogue inputs (base/rsq loads overlap gather latency).
// Non-temporal loads/stores on all streaming (zero-reuse) traffic so the L2
// keeps the bf16 gather table instead.
// emb_out == nullptr on the final layer of each graph (output never read).

__global__ void gcn_layer_kernel(const int* __restrict__ row_ptr,
                                 const int* __restrict__ col,
                                 const bf16* __restrict__ emb_in,
                                 const float* __restrict__ rsq_in,
                                 const float* __restrict__ rsq_out,
                                 const float* __restrict__ baseA,
                                 const float* __restrict__ baseB,
                                 long splitElems,
                                 float* __restrict__ sum_out,
                                 bf16* __restrict__ emb_out,
                                 int n) {
    int wave = blockIdx.x * (blockDim.x >> 6) + (threadIdx.x >> 6);
    int lane = threadIdx.x & 63;
    int q = lane & 7;                 // dim chunk
    int row = wave * 8 + (lane >> 3); // row slot
    bool act = row < n;
    int beg = 0, end = 0;
    if (act) { beg = row_ptr[row]; end = row_ptr[row + 1]; }

    // hoisted epilogue inputs (overlap gather latency); nt: no reuse
    size_t o = (size_t)row * D + (size_t)q * 8;
    float rin = act ? rsq_in[row] : 0.f;
    float ro  = (act && emb_out) ? rsq_out[row] : 0.f;
    f32x4 b0 = {0.f, 0.f, 0.f, 0.f}, b1 = {0.f, 0.f, 0.f, 0.f};
    if (act) {
        const f32x4* sp;
        if (baseA) {
            // whole row lies in exactly one of baseA/baseB (split at row granularity)
            const float* bsrc = ((size_t)row * D < (size_t)splitElems)
                                    ? (baseA + o) : (baseB + (o - splitElems));
            sp = (const f32x4*)bsrc;
        } else {
            sp = (const f32x4*)(sum_out + o);
        }
        b0 = __builtin_nontemporal_load(sp);
        b1 = __builtin_nontemporal_load(sp + 1);
    }

    float acc[8];
    #pragma unroll
    for (int k = 0; k < 8; ++k) acc[k] = 0.f;

    const int4* __restrict__ embv = (const int4*)emb_in;  // row s, chunk q at s*8+q

    int e = beg;
    for (; e + 4 <= end; e += 4) {
        int s0 = col[e];
        int s1 = col[e + 1];
        int s2 = col[e + 2];
        int s3 = col[e + 3];
        int4 w0 = embv[(size_t)s0 * 8 + q];
        int4 w1 = embv[(size_t)s1 * 8 + q];
        int4 w2 = embv[(size_t)s2 * 8 + q];
        int4 w3 = embv[(size_t)s3 * 8 + q];
        acc8(acc, w0);
        acc8(acc, w1);
        acc8(acc, w2);
        acc8(acc, w3);
    }
    for (; e < end; ++e) {
        int s0 = col[e];
        int4 w0 = embv[(size_t)s0 * 8 + q];
        acc8(acc, w0);
    }

    float vv[8];
    float ss = 0.f;
    #pragma unroll
    for (int k = 0; k < 8; ++k) {
        float v = acc[k] * rin;
        v = (v > 0.f) ? v : 0.5f * v;   // LeakyReLU(0.5)
        vv[k] = v;
        ss += v * v;
    }
    // L2-norm reduce across the 8 lanes of this row (xor within the group)
    ss += __shfl_xor(ss, 1, 64);
    ss += __shfl_xor(ss, 2, 64);
    ss += __shfl_xor(ss, 4, 64);
    float inv = 1.0f / fmaxf(sqrtf(ss), 1e-12f);

    if (act) {
        f32x4 o0, o1;
        o0.x = b0.x + vv[0] * inv;
        o0.y = b0.y + vv[1] * inv;
        o0.z = b0.z + vv[2] * inv;
        o0.w = b0.w + vv[3] * inv;
        o1.x = b1.x + vv[4] * inv;
        o1.y = b1.y + vv[5] * inv;
        o1.z = b1.z + vv[6] * inv;
        o1.w = b1.w + vv[7] * inv;
        f32x4* op = (f32x4*)(sum_out + o);
        __builtin_nontemporal_store(o0, op);
        __builtin_nontemporal_store(o1, op + 1);

        if (emb_out) {
            union { i32x4 i4; bf16 h[8]; } pk;
            #pragma unroll
            for (int k = 0; k < 8; ++k) pk.h[k] = __float2bfloat16(vv[k] * ro);
            __builtin_nontemporal_store(pk.i4, (i32x4*)(emb_out + o));
        }
    }
}

// ---------------- host side ----------------

struct GraphBufs {
    int *col, *row_ptr;
    float *rsq_out, *rsq_in;
    int *bcnt_dst, *bcnt_src;           // contiguous pair for one memset
    int *base_dst, *base_src, *cur_dst, *cur_src;
    int *binned;                        // packed (dstLocal<<19)|src
    int *binned_src;
};

static void build_graph(const int* src, const int* dst, int E, int n, int nb,
                        GraphBufs& B, hipStream_t stream) {
    (void)hipMemsetAsync(B.bcnt_dst, 0, 2 * (size_t)MAX_NB * sizeof(int), stream);
    bucket_hist2_kernel<<<512, BLK, 0, stream>>>(dst, src, E, nb,
                                                 B.bcnt_dst, B.bcnt_src);
    scan2_buckets_kernel<<<1, BLK, 0, stream>>>(B.bcnt_dst, nb, B.base_dst, B.cur_dst,
                                                B.bcnt_src, B.base_src, B.cur_src);
    bin_scatter_src_kernel<<<cdiv(E, TILE), SBLK, 0, stream>>>(
        src, E, nb, B.cur_src, B.binned_src);
    bin_scatter_kernel<<<cdiv(E, TILE), SBLK, 0, stream>>>(
        src, dst, E, nb, B.cur_dst, B.binned);
    bucket_finalize_kernel<<<2 * nb, BLK, 0, stream>>>(
        B.binned, B.base_dst, B.binned_src, B.base_src, nb, n,
        B.row_ptr, B.rsq_in, B.col, B.rsq_out);
}

extern "C" void kernel_launch(void* const* d_in, const int* in_sizes, int n_in,
                              void* d_out, int out_size, void* d_ws, size_t ws_size,
                              hipStream_t stream) {
    const float* user_emb = (const float*)d_in[0];
    const float* item_emb = (const float*)d_in[1];
    const int*   ui_src   = (const int*)d_in[2];
    const int*   ui_dst   = (const int*)d_in[3];
    const int*   uu_src   = (const int*)d_in[4];
    const int*   uu_dst   = (const int*)d_in[5];

    float* out    = (float*)d_out;
    float* ui_sum = out;                          // [N_ALL * D]
    float* uu_sum = out + (size_t)N_ALL * D;      // [N_USER * D]

    const int NB_UI = cdiv(N_ALL, RPB);   // 147
    const int NB_UU = cdiv(N_USER, RPB);  // 49

    // ws layout: embA | embB | binned (E_UI int) | binned_src (E_UI int) |
    //            UU scratch | bucket arrays
    char* wp = (char*)d_ws;
    bf16* embA = (bf16*)wp;  wp += (size_t)N_ALL * D * sizeof(bf16);   // 38.4 MB
    bf16* embB = (bf16*)wp;  wp += (size_t)N_ALL * D * sizeof(bf16);   // 38.4 MB
    int* binned = (int*)wp;     wp += (size_t)E_UI * sizeof(int);      // 12.8 MB
    int* binned_src = (int*)wp; wp += (size_t)E_UI * sizeof(int);      // 12.8 MB
    // UU scratch (used only in UU phase)
    int*   uu_col     = (int*)wp;   wp += (size_t)E_UU * sizeof(int);        // 6.4 MB
    int*   uu_row_ptr = (int*)wp;   wp += (size_t)(N_USER + 1) * sizeof(int);
    float* uu_rsq_out = (float*)wp; wp += (size_t)N_USER * sizeof(float);
    float* uu_rsq_in  = (float*)wp; wp += (size_t)N_USER * sizeof(float);
    // shared small bucket arrays (bcnt_dst, bcnt_src contiguous for one memset)
    int* bcnt_dst = (int*)wp;  wp += (size_t)MAX_NB * sizeof(int);
    int* bcnt_src = (int*)wp;  wp += (size_t)MAX_NB * sizeof(int);
    int* base_dst = (int*)wp;  wp += (size_t)(MAX_NB + 1) * sizeof(int);
    int* base_src = (int*)wp;  wp += (size_t)(MAX_NB + 1) * sizeof(int);
    int* cur_dst  = (int*)wp;  wp += (size_t)MAX_NB * sizeof(int);
    int* cur_src  = (int*)wp;  wp += (size_t)MAX_NB * sizeof(int);

    const int ROWS_PER_BLK = (BLK / 64) * 8;  // 32

    // ---------------- user-item graph ----------------
    {
        // UI CSR scratch lives in the uu_sum region of d_out (dead during UI phase).
        char* p = (char*)uu_sum;
        GraphBufs UI;
        UI.col      = (int*)p;   p += (size_t)E_UI * sizeof(int);          // 12.8 MB
        UI.row_ptr  = (int*)p;   p += (size_t)(N_ALL + 1) * sizeof(int);   // 1.2 MB
        UI.rsq_out  = (float*)p; p += (size_t)N_ALL * sizeof(float);       // 1.2 MB
        UI.rsq_in   = (float*)p; p += (size_t)N_ALL * sizeof(float);       // 1.2 MB
        UI.bcnt_dst = bcnt_dst; UI.bcnt_src = bcnt_src;
        UI.base_dst = base_dst; UI.base_src = base_src;
        UI.cur_dst  = cur_dst;  UI.cur_src  = cur_src;
        UI.binned = binned;
        UI.binned_src = binned_src;

        build_graph(ui_src, ui_dst, E_UI, N_ALL, NB_UI, UI, stream);

        size_t tot = (size_t)N_ALL * D;
        init_ui_kernel<<<cdiv((int)tot, BLK), BLK, 0, stream>>>(
            user_emb, item_emb, UI.rsq_out, embA);

        bf16* bufs[2] = {embA, embB};
        for (int l = 0; l < 3; ++l) {
            const float* bA = (l == 0) ? user_emb : nullptr;
            const float* bB = (l == 0) ? item_emb : nullptr;
            bf16* eout = (l == 2) ? nullptr : bufs[(l + 1) & 1];
            gcn_layer_kernel<<<cdiv(N_ALL, ROWS_PER_BLK), BLK, 0, stream>>>(
                UI.row_ptr, UI.col, bufs[l & 1], UI.rsq_in, UI.rsq_out,
                bA, bB, (long)N_USER * D,
                ui_sum, eout, N_ALL);
        }
    }

    // ---------------- user-user graph ----------------
    {
        GraphBufs UU;
        UU.col = uu_col;
        UU.row_ptr = uu_row_ptr;
        UU.rsq_out = uu_rsq_out;
        UU.rsq_in = uu_rsq_in;
        UU.bcnt_dst = bcnt_dst; UU.bcnt_src = bcnt_src;
        UU.base_dst = base_dst; UU.base_src = base_src;
        UU.cur_dst  = cur_dst;  UU.cur_src  = cur_src;
        UU.binned = binned;             // reuse (only first E_UU entries)
        UU.binned_src = binned_src;

        build_graph(uu_src, uu_dst, E_UU, N_USER, NB_UU, UU, stream);

        size_t tot = (size_t)N_USER * D;
        init_uu_kernel<<<cdiv((int)tot, BLK), BLK, 0, stream>>>(
            user_emb, UU.rsq_out, embA);

        bf16* bufs[2] = {embA, embB};
        for (int l = 0; l < 2; ++l) {
            const float* bA = (l == 0) ? user_emb : nullptr;
            bf16* eout = (l == 1) ? nullptr : bufs[(l + 1) & 1];
            gcn_layer_kernel<<<cdiv(N_USER, ROWS_PER_BLK), BLK, 0, stream>>>(
                UU.row_ptr, UU.col, bufs[l & 1], UU.rsq_in, UU.rsq_out,
                bA, nullptr, (long)N_USER * D,
                uu_sum, eout, N_USER);
        }
    }
}

// Round 12
// 584.188 us; speedup vs baseline: 1.1598x; 1.1598x over previous
//
#include <hip/hip_runtime.h>
#include <hip/hip_bf16.h>

constexpr int N_USER = 100000;
constexpr int N_ITEM = 200000;
constexpr int N_ALL  = N_USER + N_ITEM;
constexpr int E_UI   = 3200000;
constexpr int E_UU   = 1600000;
constexpr int D      = 64;
constexpr int BLK    = 256;

// bucketing: 2048 rows per bucket (nb_UI = 147)
constexpr int RPB_SHIFT = 11;
constexpr int RPB       = 1 << RPB_SHIFT;   // 2048
constexpr int MAX_NB    = 160;              // >= cdiv(N_ALL, RPB) = 147
constexpr int SRC_BITS  = 19;               // N_ALL < 2^19
constexpr int SRC_MASK  = (1 << SRC_BITS) - 1;

// merged bin_scatter tile geometry (LDS only 4*160*4B = 2.5 KB at nb<=160)
constexpr int SBLK = 512;
constexpr int EPT  = 16;
constexpr int TILE = SBLK * EPT;            // 8192 edges per block

// finalize block size (16 waves to hide the two serial per-bucket passes)
constexpr int FBLK = 1024;

typedef __hip_bfloat16 bf16;
typedef float f32x4 __attribute__((ext_vector_type(4)));
typedef int   i32x4 __attribute__((ext_vector_type(4)));

// ---------------- small helpers ----------------

__device__ inline int wave_incl_scan(int x, int lane) {
    #pragma unroll
    for (int off = 1; off < 64; off <<= 1) {
        int y = __shfl_up(x, off, 64);
        if (lane >= off) x += y;
    }
    return x;
}

static inline int cdiv(int a, int b) { return (a + b - 1) / b; }

// accumulate 8 bf16 (packed in an int4) into 8 f32 accumulators
__device__ inline void acc8(float* acc, const int4 v) {
    acc[0] += __int_as_float(v.x << 16);
    acc[1] += __int_as_float(v.x & 0xffff0000);
    acc[2] += __int_as_float(v.y << 16);
    acc[3] += __int_as_float(v.y & 0xffff0000);
    acc[4] += __int_as_float(v.z << 16);
    acc[5] += __int_as_float(v.z & 0xffff0000);
    acc[6] += __int_as_float(v.w << 16);
    acc[7] += __int_as_float(v.w & 0xffff0000);
}

// ---------------- init kernels (scaled bf16 emb only; sums fused into layer 1) ----------------

__global__ void init_ui_kernel(const float* __restrict__ ue,
                               const float* __restrict__ ie,
                               const float* __restrict__ rsq_out,
                               bf16* __restrict__ emb_scaled) {
    size_t t = (size_t)blockIdx.x * blockDim.x + threadIdx.x;
    const size_t total = (size_t)N_ALL * D;
    if (t >= total) return;
    const size_t userN = (size_t)N_USER * D;
    float v = (t < userN) ? ue[t] : ie[t - userN];
    int row = (int)(t >> 6);
    emb_scaled[t] = __float2bfloat16(v * rsq_out[row]);
}

__global__ void init_uu_kernel(const float* __restrict__ ue,
                               const float* __restrict__ rsq_out,
                               bf16* __restrict__ emb_scaled) {
    size_t t = (size_t)blockIdx.x * blockDim.x + threadIdx.x;
    const size_t total = (size_t)N_USER * D;
    if (t >= total) return;
    float v = ue[t];
    int row = (int)(t >> 6);
    emb_scaled[t] = __float2bfloat16(v * rsq_out[row]);
}

// ---------------- bucket histograms (both sides in one pass) ----------------

__global__ void bucket_hist2_kernel(const int* __restrict__ dst,
                                    const int* __restrict__ src, int E, int nb,
                                    int* __restrict__ bcntD_g,
                                    int* __restrict__ bcntS_g) {
    __shared__ int cD[MAX_NB];
    __shared__ int cS[MAX_NB];
    for (int b = threadIdx.x; b < nb; b += blockDim.x) { cD[b] = 0; cS[b] = 0; }
    __syncthreads();
    for (int e = blockIdx.x * blockDim.x + threadIdx.x; e < E;
         e += gridDim.x * blockDim.x) {
        atomicAdd(&cD[dst[e] >> RPB_SHIFT], 1);
        atomicAdd(&cS[src[e] >> RPB_SHIFT], 1);
    }
    __syncthreads();
    for (int b = threadIdx.x; b < nb; b += blockDim.x) {
        if (cD[b]) atomicAdd(&bcntD_g[b], cD[b]);
        if (cS[b]) atomicAdd(&bcntS_g[b], cS[b]);
    }
}

// ---------------- single-block exclusive scans (dst + src in one launch) ----------------

__device__ void scan_one(const int* __restrict__ cnt, int nb,
                         int* __restrict__ base, int* __restrict__ cursor,
                         int* wsum, int* carry_s) {
    int t = threadIdx.x, lane = t & 63, wid = t >> 6;
    if (t == 0) *carry_s = 0;
    for (int b0 = 0; b0 < nb; b0 += BLK) {
        __syncthreads();
        int i = b0 + t;
        int x = (i < nb) ? cnt[i] : 0;
        int s = wave_incl_scan(x, lane);
        if (lane == 63) wsum[wid] = s;
        __syncthreads();
        int add = *carry_s;
        for (int w = 0; w < wid; ++w) add += wsum[w];
        int excl = add + s - x;
        if (i < nb) { base[i] = excl; cursor[i] = excl; }
        int total = wsum[0] + wsum[1] + wsum[2] + wsum[3];
        __syncthreads();
        if (t == 0) *carry_s = add + total;  // add == old carry for t0
    }
    __syncthreads();
    if (t == 0) base[nb] = *carry_s;
    __syncthreads();
}

__global__ void scan2_buckets_kernel(const int* __restrict__ cntD, int nb,
                                     int* __restrict__ baseD, int* __restrict__ curD,
                                     const int* __restrict__ cntS,
                                     int* __restrict__ baseS, int* __restrict__ curS) {
    __shared__ int wsum[4];
    __shared__ int carry_s;
    scan_one(cntD, nb, baseD, curD, wsum, &carry_s);
    scan_one(cntS, nb, baseS, curS, wsum, &carry_s);
}

// ---------------- merged bin scatter: both sides in one edge pass ----------------
// dst record packed as (dstLocal << SRC_BITS) | src.

__global__ __launch_bounds__(SBLK) void bin_scatter2_kernel(
    const int* __restrict__ src, const int* __restrict__ dst, int E, int nb,
    int* __restrict__ curS, int* __restrict__ curD,
    int* __restrict__ binned_src, int* __restrict__ binned) {
    __shared__ int cS[MAX_NB];
    __shared__ int bS[MAX_NB];
    __shared__ int cD[MAX_NB];
    __shared__ int bD[MAX_NB];
    int t = threadIdx.x;
    for (int b = t; b < nb; b += SBLK) { cS[b] = 0; cD[b] = 0; }
    __syncthreads();
    int base_e = blockIdx.x * TILE;
    int mys[EPT], myd[EPT], myrS[EPT], myrD[EPT];
    #pragma unroll
    for (int j = 0; j < EPT; ++j) {
        int e = base_e + j * SBLK + t;
        if (e < E) {
            int s = src[e];
            int d = dst[e];
            mys[j] = s;
            myd[j] = d;
            myrS[j] = atomicAdd(&cS[s >> RPB_SHIFT], 1);
            myrD[j] = atomicAdd(&cD[d >> RPB_SHIFT], 1);
        } else {
            myd[j] = -1;
        }
    }
    __syncthreads();
    for (int b = t; b < nb; b += SBLK) {
        if (cS[b] > 0) bS[b] = atomicAdd(&curS[b], cS[b]);
        if (cD[b] > 0) bD[b] = atomicAdd(&curD[b], cD[b]);
    }
    __syncthreads();
    #pragma unroll
    for (int j = 0; j < EPT; ++j) {
        if (myd[j] >= 0) {
            int s = mys[j], d = myd[j];
            binned_src[bS[s >> RPB_SHIFT] + myrS[j]] = s;
            binned[bD[d >> RPB_SHIFT] + myrD[j]] =
                ((d & (RPB - 1)) << SRC_BITS) | s;
        }
    }
}

// ---------------- merged per-bucket finalize (1024 threads = 16 waves) ----------------
// blocks [0, nb): dst-side CSR (row_ptr, rsq_in, col) from packed binned
// blocks [nb, 2nb): src-side degree -> rsq_out

__global__ __launch_bounds__(FBLK) void bucket_finalize_kernel(
    const int* __restrict__ binned,
    const int* __restrict__ baseD,
    const int* __restrict__ binned_src,
    const int* __restrict__ baseS,
    int nb, int n,
    int* __restrict__ row_ptr,
    float* __restrict__ rsq_in,
    int* __restrict__ col,
    float* __restrict__ rsq_out) {
    __shared__ int deg[RPB];
    __shared__ int cur[RPB];
    __shared__ int wsum[FBLK / 64];
    __shared__ int carry;
    int bb = blockIdx.x;
    int t = threadIdx.x, lane = t & 63, wid = t >> 6;

    if (bb >= nb) {
        // ---- src side: out-degree -> rsq_out ----
        int b = bb - nb;
        int row0 = b << RPB_SHIFT;
        for (int i = t; i < RPB; i += FBLK) deg[i] = 0;
        __syncthreads();
        int beg = baseS[b], end = baseS[b + 1];
        for (int e = beg + t; e < end; e += FBLK)
            atomicAdd(&deg[binned_src[e] - row0], 1);
        __syncthreads();
        for (int i = t; i < RPB; i += FBLK)
            if (row0 + i < n)
                rsq_out[row0 + i] = 1.0f / sqrtf(fmaxf((float)deg[i], 1.0f));
        return;
    }

    // ---- dst side: CSR ----
    int b = bb;
    int row0 = b << RPB_SHIFT;
    int nrows = min(RPB, n - row0);
    int beg = baseD[b], end = baseD[b + 1];

    for (int i = t; i < RPB; i += FBLK) deg[i] = 0;
    __syncthreads();

    for (int e = beg + t; e < end; e += FBLK)
        atomicAdd(&deg[binned[e] >> SRC_BITS], 1);

    // chunked exclusive scan of deg[0..RPB) -> cur (absolute), row_ptr, rsq_in
    if (t == 0) carry = 0;
    for (int c0 = 0; c0 < RPB; c0 += FBLK) {
        __syncthreads();
        int x = deg[c0 + t];
        int s = wave_incl_scan(x, lane);
        if (lane == 63) wsum[wid] = s;
        __syncthreads();
        int add = carry;
        for (int w = 0; w < wid; ++w) add += wsum[w];
        int excl = add + s - x;
        cur[c0 + t] = beg + excl;
        if (c0 + t < nrows) {
            row_ptr[row0 + c0 + t] = beg + excl;
            rsq_in[row0 + c0 + t] = 1.0f / sqrtf(fmaxf((float)x, 1.0f));
        }
        int total = 0;
        #pragma unroll
        for (int w = 0; w < FBLK / 64; ++w) total += wsum[w];
        __syncthreads();
        if (t == 0) carry = add + total;  // add == old carry for t0
    }
    __syncthreads();
    if (b == nb - 1 && t == 0) row_ptr[n] = end;
    __syncthreads();

    for (int e = beg + t; e < end; e += FBLK) {
        int p = binned[e];
        int pos = atomicAdd(&cur[p >> SRC_BITS], 1);
        col[pos] = p & SRC_MASK;
    }
}

// ---------------- fused GCN layer: 8 rows/wave, 8 lanes/row ----------------
// Hoisted epilogue inputs (base/rsq loads overlap gather latency).
// Non-temporal loads/stores on all streaming (zero-reuse) traffic so the L2
// keeps the bf16 gather table instead.
// emb_out == nullptr on the final layer of each graph (output never read).

__global__ void gcn_layer_kernel(const int* __restrict__ row_ptr,
                                 const int* __restrict__ col,
                                 const bf16* __restrict__ emb_in,
                                 const float* __restrict__ rsq_in,
                                 const float* __restrict__ rsq_out,
                                 const float* __restrict__ baseA,
                                 const float* __restrict__ baseB,
                                 long splitElems,
                                 float* __restrict__ sum_out,
                                 bf16* __restrict__ emb_out,
                                 int n) {
    int wave = blockIdx.x * (blockDim.x >> 6) + (threadIdx.x >> 6);
    int lane = threadIdx.x & 63;
    int q = lane & 7;                 // dim chunk
    int row = wave * 8 + (lane >> 3); // row slot
    bool act = row < n;
    int beg = 0, end = 0;
    if (act) { beg = row_ptr[row]; end = row_ptr[row + 1]; }

    // hoisted epilogue inputs (overlap gather latency); nt: no reuse
    size_t o = (size_t)row * D + (size_t)q * 8;
    float rin = act ? rsq_in[row] : 0.f;
    float ro  = (act && emb_out) ? rsq_out[row] : 0.f;
    f32x4 b0 = {0.f, 0.f, 0.f, 0.f}, b1 = {0.f, 0.f, 0.f, 0.f};
    if (act) {
        const f32x4* sp;
        if (baseA) {
            // whole row lies in exactly one of baseA/baseB (split at row granularity)
            const float* bsrc = ((size_t)row * D < (size_t)splitElems)
                                    ? (baseA + o) : (baseB + (o - splitElems));
            sp = (const f32x4*)bsrc;
        } else {
            sp = (const f32x4*)(sum_out + o);
        }
        b0 = __builtin_nontemporal_load(sp);
        b1 = __builtin_nontemporal_load(sp + 1);
    }

    float acc[8];
    #pragma unroll
    for (int k = 0; k < 8; ++k) acc[k] = 0.f;

    const int4* __restrict__ embv = (const int4*)emb_in;  // row s, chunk q at s*8+q

    int e = beg;
    for (; e + 4 <= end; e += 4) {
        int s0 = col[e];
        int s1 = col[e + 1];
        int s2 = col[e + 2];
        int s3 = col[e + 3];
        int4 w0 = embv[(size_t)s0 * 8 + q];
        int4 w1 = embv[(size_t)s1 * 8 + q];
        int4 w2 = embv[(size_t)s2 * 8 + q];
        int4 w3 = embv[(size_t)s3 * 8 + q];
        acc8(acc, w0);
        acc8(acc, w1);
        acc8(acc, w2);
        acc8(acc, w3);
    }
    for (; e < end; ++e) {
        int s0 = col[e];
        int4 w0 = embv[(size_t)s0 * 8 + q];
        acc8(acc, w0);
    }

    float vv[8];
    float ss = 0.f;
    #pragma unroll
    for (int k = 0; k < 8; ++k) {
        float v = acc[k] * rin;
        v = (v > 0.f) ? v : 0.5f * v;   // LeakyReLU(0.5)
        vv[k] = v;
        ss += v * v;
    }
    // L2-norm reduce across the 8 lanes of this row (xor within the group)
    ss += __shfl_xor(ss, 1, 64);
    ss += __shfl_xor(ss, 2, 64);
    ss += __shfl_xor(ss, 4, 64);
    float inv = 1.0f / fmaxf(sqrtf(ss), 1e-12f);

    if (act) {
        f32x4 o0, o1;
        o0.x = b0.x + vv[0] * inv;
        o0.y = b0.y + vv[1] * inv;
        o0.z = b0.z + vv[2] * inv;
        o0.w = b0.w + vv[3] * inv;
        o1.x = b1.x + vv[4] * inv;
        o1.y = b1.y + vv[5] * inv;
        o1.z = b1.z + vv[6] * inv;
        o1.w = b1.w + vv[7] * inv;
        f32x4* op = (f32x4*)(sum_out + o);
        __builtin_nontemporal_store(o0, op);
        __builtin_nontemporal_store(o1, op + 1);

        if (emb_out) {
            union { i32x4 i4; bf16 h[8]; } pk;
            #pragma unroll
            for (int k = 0; k < 8; ++k) pk.h[k] = __float2bfloat16(vv[k] * ro);
            __builtin_nontemporal_store(pk.i4, (i32x4*)(emb_out + o));
        }
    }
}

// ---------------- host side ----------------

struct GraphBufs {
    int *col, *row_ptr;
    float *rsq_out, *rsq_in;
    int *bcnt_dst, *bcnt_src;           // contiguous pair for one memset
    int *base_dst, *base_src, *cur_dst, *cur_src;
    int *binned;                        // packed (dstLocal<<19)|src
    int *binned_src;
};

static void build_graph(const int* src, const int* dst, int E, int n, int nb,
                        GraphBufs& B, hipStream_t stream) {
    (void)hipMemsetAsync(B.bcnt_dst, 0, 2 * (size_t)MAX_NB * sizeof(int), stream);
    bucket_hist2_kernel<<<512, BLK, 0, stream>>>(dst, src, E, nb,
                                                 B.bcnt_dst, B.bcnt_src);
    scan2_buckets_kernel<<<1, BLK, 0, stream>>>(B.bcnt_dst, nb, B.base_dst, B.cur_dst,
                                                B.bcnt_src, B.base_src, B.cur_src);
    bin_scatter2_kernel<<<cdiv(E, TILE), SBLK, 0, stream>>>(
        src, dst, E, nb, B.cur_src, B.cur_dst, B.binned_src, B.binned);
    bucket_finalize_kernel<<<2 * nb, FBLK, 0, stream>>>(
        B.binned, B.base_dst, B.binned_src, B.base_src, nb, n,
        B.row_ptr, B.rsq_in, B.col, B.rsq_out);
}

extern "C" void kernel_launch(void* const* d_in, const int* in_sizes, int n_in,
                              void* d_out, int out_size, void* d_ws, size_t ws_size,
                              hipStream_t stream) {
    const float* user_emb = (const float*)d_in[0];
    const float* item_emb = (const float*)d_in[1];
    const int*   ui_src   = (const int*)d_in[2];
    const int*   ui_dst   = (const int*)d_in[3];
    const int*   uu_src   = (const int*)d_in[4];
    const int*   uu_dst   = (const int*)d_in[5];

    float* out    = (float*)d_out;
    float* ui_sum = out;                          // [N_ALL * D]
    float* uu_sum = out + (size_t)N_ALL * D;      // [N_USER * D]

    const int NB_UI = cdiv(N_ALL, RPB);   // 147
    const int NB_UU = cdiv(N_USER, RPB);  // 49

    // ws layout: embA | embB | binned (E_UI int) | binned_src (E_UI int) |
    //            UU scratch | bucket arrays
    char* wp = (char*)d_ws;
    bf16* embA = (bf16*)wp;  wp += (size_t)N_ALL * D * sizeof(bf16);   // 38.4 MB
    bf16* embB = (bf16*)wp;  wp += (size_t)N_ALL * D * sizeof(bf16);   // 38.4 MB
    int* binned = (int*)wp;     wp += (size_t)E_UI * sizeof(int);      // 12.8 MB
    int* binned_src = (int*)wp; wp += (size_t)E_UI * sizeof(int);      // 12.8 MB
    // UU scratch (used only in UU phase)
    int*   uu_col     = (int*)wp;   wp += (size_t)E_UU * sizeof(int);        // 6.4 MB
    int*   uu_row_ptr = (int*)wp;   wp += (size_t)(N_USER + 1) * sizeof(int);
    float* uu_rsq_out = (float*)wp; wp += (size_t)N_USER * sizeof(float);
    float* uu_rsq_in  = (float*)wp; wp += (size_t)N_USER * sizeof(float);
    // shared small bucket arrays (bcnt_dst, bcnt_src contiguous for one memset)
    int* bcnt_dst = (int*)wp;  wp += (size_t)MAX_NB * sizeof(int);
    int* bcnt_src = (int*)wp;  wp += (size_t)MAX_NB * sizeof(int);
    int* base_dst = (int*)wp;  wp += (size_t)(MAX_NB + 1) * sizeof(int);
    int* base_src = (int*)wp;  wp += (size_t)(MAX_NB + 1) * sizeof(int);
    int* cur_dst  = (int*)wp;  wp += (size_t)MAX_NB * sizeof(int);
    int* cur_src  = (int*)wp;  wp += (size_t)MAX_NB * sizeof(int);

    const int ROWS_PER_BLK = (BLK / 64) * 8;  // 32

    // ---------------- user-item graph ----------------
    {
        // UI CSR scratch lives in the uu_sum region of d_out (dead during UI phase).
        char* p = (char*)uu_sum;
        GraphBufs UI;
        UI.col      = (int*)p;   p += (size_t)E_UI * sizeof(int);          // 12.8 MB
        UI.row_ptr  = (int*)p;   p += (size_t)(N_ALL + 1) * sizeof(int);   // 1.2 MB
        UI.rsq_out  = (float*)p; p += (size_t)N_ALL * sizeof(float);       // 1.2 MB
        UI.rsq_in   = (float*)p; p += (size_t)N_ALL * sizeof(float);       // 1.2 MB
        UI.bcnt_dst = bcnt_dst; UI.bcnt_src = bcnt_src;
        UI.base_dst = base_dst; UI.base_src = base_src;
        UI.cur_dst  = cur_dst;  UI.cur_src  = cur_src;
        UI.binned = binned;
        UI.binned_src = binned_src;

        build_graph(ui_src, ui_dst, E_UI, N_ALL, NB_UI, UI, stream);

        size_t tot = (size_t)N_ALL * D;
        init_ui_kernel<<<cdiv((int)tot, BLK), BLK, 0, stream>>>(
            user_emb, item_emb, UI.rsq_out, embA);

        bf16* bufs[2] = {embA, embB};
        for (int l = 0; l < 3; ++l) {
            const float* bA = (l == 0) ? user_emb : nullptr;
            const float* bB = (l == 0) ? item_emb : nullptr;
            bf16* eout = (l == 2) ? nullptr : bufs[(l + 1) & 1];
            gcn_layer_kernel<<<cdiv(N_ALL, ROWS_PER_BLK), BLK, 0, stream>>>(
                UI.row_ptr, UI.col, bufs[l & 1], UI.rsq_in, UI.rsq_out,
                bA, bB, (long)N_USER * D,
                ui_sum, eout, N_ALL);
        }
    }

    // ---------------- user-user graph ----------------
    {
        GraphBufs UU;
        UU.col = uu_col;
        UU.row_ptr = uu_row_ptr;
        UU.rsq_out = uu_rsq_out;
        UU.rsq_in = uu_rsq_in;
        UU.bcnt_dst = bcnt_dst; UU.bcnt_src = bcnt_src;
        UU.base_dst = base_dst; UU.base_src = base_src;
        UU.cur_dst  = cur_dst;  UU.cur_src  = cur_src;
        UU.binned = binned;             // reuse (only first E_UU entries)
        UU.binned_src = binned_src;

        build_graph(uu_src, uu_dst, E_UU, N_USER, NB_UU, UU, stream);

        size_t tot = (size_t)N_USER * D;
        init_uu_kernel<<<cdiv((int)tot, BLK), BLK, 0, stream>>>(
            user_emb, UU.rsq_out, embA);

        bf16* bufs[2] = {embA, embB};
        for (int l = 0; l < 2; ++l) {
            const float* bA = (l == 0) ? user_emb : nullptr;
            bf16* eout = (l == 1) ? nullptr : bufs[(l + 1) & 1];
            gcn_layer_kernel<<<cdiv(N_USER, ROWS_PER_BLK), BLK, 0, stream>>>(
                UU.row_ptr, UU.col, bufs[l & 1], UU.rsq_in, UU.rsq_out,
                bA, nullptr, (long)N_USER * D,
                uu_sum, eout, N_USER);
        }
    }
}

// Round 13
// 520.872 us; speedup vs baseline: 1.3008x; 1.1216x over previous
//
#include <hip/hip_runtime.h>
#include <hip/hip_bf16.h>

constexpr int N_USER = 100000;
constexpr int N_ITEM = 200000;
constexpr int N_ALL  = N_USER + N_ITEM;
constexpr int E_UI   = 3200000;
constexpr int E_UU   = 1600000;
constexpr int D      = 64;
constexpr int BLK    = 256;

// bucketing: 2048 rows per bucket
constexpr int RPB_SHIFT = 11;
constexpr int RPB       = 1 << RPB_SHIFT;   // 2048
constexpr int MAX_NB    = 160;
constexpr int SRC_BITS  = 19;               // N_ALL < 2^19
constexpr int SRC_MASK  = (1 << SRC_BITS) - 1;

// bin_scatter tile geometry
constexpr int SBLK = 512;
constexpr int EPT  = 16;
constexpr int TILE = SBLK * EPT;            // 8192 edges per block

constexpr int FBLK = 1024;                  // finalize block (16 waves)

constexpr int NB_UI = (N_ALL  + RPB - 1) / RPB;  // 147
constexpr int NB_UU = (N_USER + RPB - 1) / RPB;  // 49
constexpr int T_UI  = (E_UI + TILE - 1) / TILE;  // 391
constexpr int T_UU  = (E_UU + TILE - 1) / TILE;  // 196
constexpr int H_UI  = 384;                  // hist blocks for UI
constexpr int H_UU  = 128;                  // hist blocks for UU

typedef __hip_bfloat16 bf16;
typedef float f32x4 __attribute__((ext_vector_type(4)));
typedef int   i32x4 __attribute__((ext_vector_type(4)));

// ---------------- small helpers ----------------

__device__ inline int wave_incl_scan(int x, int lane) {
    #pragma unroll
    for (int off = 1; off < 64; off <<= 1) {
        int y = __shfl_up(x, off, 64);
        if (lane >= off) x += y;
    }
    return x;
}

static inline int cdiv(int a, int b) { return (a + b - 1) / b; }

// accumulate 8 bf16 (packed in an int4) into 8 f32 accumulators
__device__ inline void acc8(float* acc, const int4 v) {
    acc[0] += __int_as_float(v.x << 16);
    acc[1] += __int_as_float(v.x & 0xffff0000);
    acc[2] += __int_as_float(v.y << 16);
    acc[3] += __int_as_float(v.y & 0xffff0000);
    acc[4] += __int_as_float(v.z << 16);
    acc[5] += __int_as_float(v.z & 0xffff0000);
    acc[6] += __int_as_float(v.w << 16);
    acc[7] += __int_as_float(v.w & 0xffff0000);
}

__device__ inline void unpack8(const i32x4 v, float* f) {
    f[0] = __int_as_float(v.x << 16);
    f[1] = __int_as_float(v.x & 0xffff0000);
    f[2] = __int_as_float(v.y << 16);
    f[3] = __int_as_float(v.y & 0xffff0000);
    f[4] = __int_as_float(v.z << 16);
    f[5] = __int_as_float(v.z & 0xffff0000);
    f[6] = __int_as_float(v.w << 16);
    f[7] = __int_as_float(v.w & 0xffff0000);
}

// L2-norm inverse across the 8 lanes of one row slot
__device__ inline float groupnorm_inv(const float* f) {
    float ss = 0.f;
    #pragma unroll
    for (int k = 0; k < 8; ++k) ss += f[k] * f[k];
    ss += __shfl_xor(ss, 1, 64);
    ss += __shfl_xor(ss, 2, 64);
    ss += __shfl_xor(ss, 4, 64);
    return 1.0f / fmaxf(sqrtf(ss), 1e-12f);
}

// ---------------- init kernels ----------------

__global__ void init_ui_kernel(const float* __restrict__ ue,
                               const float* __restrict__ ie,
                               const float* __restrict__ rsq_out,
                               bf16* __restrict__ emb_scaled) {
    size_t t = (size_t)blockIdx.x * blockDim.x + threadIdx.x;
    const size_t total = (size_t)N_ALL * D;
    if (t >= total) return;
    const size_t userN = (size_t)N_USER * D;
    float v = (t < userN) ? ue[t] : ie[t - userN];
    int row = (int)(t >> 6);
    emb_scaled[t] = __float2bfloat16(v * rsq_out[row]);
}

__global__ void init_uu_kernel(const float* __restrict__ ue,
                               const float* __restrict__ rsq_out,
                               bf16* __restrict__ emb_scaled) {
    size_t t = (size_t)blockIdx.x * blockDim.x + threadIdx.x;
    const size_t total = (size_t)N_USER * D;
    if (t >= total) return;
    float v = ue[t];
    int row = (int)(t >> 6);
    emb_scaled[t] = __float2bfloat16(v * rsq_out[row]);
}

// ---------------- merged bucket histogram: both graphs, both sides ----------------
// bc layout: [UI_D | UI_S | UU_D | UU_S], each MAX_NB ints.

__global__ void bucket_hist_both_kernel(const int* __restrict__ ui_src,
                                        const int* __restrict__ ui_dst,
                                        const int* __restrict__ uu_src,
                                        const int* __restrict__ uu_dst,
                                        int* __restrict__ bc) {
    __shared__ int cD[MAX_NB];
    __shared__ int cS[MAX_NB];
    bool isUI = blockIdx.x < H_UI;
    const int* src = isUI ? ui_src : uu_src;
    const int* dst = isUI ? ui_dst : uu_dst;
    int E  = isUI ? E_UI : E_UU;
    int nb = isUI ? NB_UI : NB_UU;
    int* gD = bc + (isUI ? 0 : 2 * MAX_NB);
    int* gS = gD + MAX_NB;
    int bi  = isUI ? blockIdx.x : blockIdx.x - H_UI;
    int nbk = isUI ? H_UI : H_UU;
    for (int b = threadIdx.x; b < nb; b += BLK) { cD[b] = 0; cS[b] = 0; }
    __syncthreads();
    for (int e = bi * BLK + threadIdx.x; e < E; e += nbk * BLK) {
        atomicAdd(&cD[dst[e] >> RPB_SHIFT], 1);
        atomicAdd(&cS[src[e] >> RPB_SHIFT], 1);
    }
    __syncthreads();
    for (int b = threadIdx.x; b < nb; b += BLK) {
        if (cD[b]) atomicAdd(&gD[b], cD[b]);
        if (cS[b]) atomicAdd(&gS[b], cS[b]);
    }
}

// ---------------- single-block exclusive scans (all 4 arrays) ----------------

__device__ void scan_one(const int* __restrict__ cnt, int nb,
                         int* __restrict__ base, int* __restrict__ cursor,
                         int* wsum, int* carry_s) {
    int t = threadIdx.x, lane = t & 63, wid = t >> 6;
    if (t == 0) *carry_s = 0;
    for (int b0 = 0; b0 < nb; b0 += BLK) {
        __syncthreads();
        int i = b0 + t;
        int x = (i < nb) ? cnt[i] : 0;
        int s = wave_incl_scan(x, lane);
        if (lane == 63) wsum[wid] = s;
        __syncthreads();
        int add = *carry_s;
        for (int w = 0; w < wid; ++w) add += wsum[w];
        int excl = add + s - x;
        if (i < nb) { base[i] = excl; cursor[i] = excl; }
        int total = wsum[0] + wsum[1] + wsum[2] + wsum[3];
        __syncthreads();
        if (t == 0) *carry_s = add + total;  // add == old carry for t0
    }
    __syncthreads();
    if (t == 0) base[nb] = *carry_s;
    __syncthreads();
}

// bases: 4 arrays of (MAX_NB+1); curs: 4 arrays of MAX_NB (same order as bc)
__global__ void scan4_kernel(const int* __restrict__ bc,
                             int* __restrict__ bases,
                             int* __restrict__ curs) {
    __shared__ int wsum[4];
    __shared__ int carry_s;
    scan_one(bc + 0 * MAX_NB, NB_UI, bases + 0 * (MAX_NB + 1), curs + 0 * MAX_NB, wsum, &carry_s);
    scan_one(bc + 1 * MAX_NB, NB_UI, bases + 1 * (MAX_NB + 1), curs + 1 * MAX_NB, wsum, &carry_s);
    scan_one(bc + 2 * MAX_NB, NB_UU, bases + 2 * (MAX_NB + 1), curs + 2 * MAX_NB, wsum, &carry_s);
    scan_one(bc + 3 * MAX_NB, NB_UU, bases + 3 * (MAX_NB + 1), curs + 3 * MAX_NB, wsum, &carry_s);
}

// ---------------- merged bin scatter: both graphs, both sides, one edge pass ----------------
// dst record packed as (dstLocal << SRC_BITS) | src.

__global__ __launch_bounds__(SBLK) void bin_scatter2_both_kernel(
    const int* __restrict__ ui_src, const int* __restrict__ ui_dst,
    const int* __restrict__ uu_src, const int* __restrict__ uu_dst,
    int* __restrict__ curs,
    int* __restrict__ ui_binned_src, int* __restrict__ ui_binned,
    int* __restrict__ uu_binned_src, int* __restrict__ uu_binned) {
    __shared__ int cS[MAX_NB];
    __shared__ int bS[MAX_NB];
    __shared__ int cD[MAX_NB];
    __shared__ int bD[MAX_NB];
    bool isUI = blockIdx.x < T_UI;
    const int* src = isUI ? ui_src : uu_src;
    const int* dst = isUI ? ui_dst : uu_dst;
    int E  = isUI ? E_UI : E_UU;
    int nb = isUI ? NB_UI : NB_UU;
    int* curD = curs + (isUI ? 0 : 2 * MAX_NB);
    int* curS = curD + MAX_NB;
    int* bsrc = isUI ? ui_binned_src : uu_binned_src;
    int* bpk  = isUI ? ui_binned : uu_binned;
    int ti = isUI ? blockIdx.x : blockIdx.x - T_UI;

    int t = threadIdx.x;
    for (int b = t; b < nb; b += SBLK) { cS[b] = 0; cD[b] = 0; }
    __syncthreads();
    int base_e = ti * TILE;
    int mys[EPT], myd[EPT], myrS[EPT], myrD[EPT];
    #pragma unroll
    for (int j = 0; j < EPT; ++j) {
        int e = base_e + j * SBLK + t;
        if (e < E) {
            int s = src[e];
            int d = dst[e];
            mys[j] = s;
            myd[j] = d;
            myrS[j] = atomicAdd(&cS[s >> RPB_SHIFT], 1);
            myrD[j] = atomicAdd(&cD[d >> RPB_SHIFT], 1);
        } else {
            myd[j] = -1;
        }
    }
    __syncthreads();
    for (int b = t; b < nb; b += SBLK) {
        if (cS[b] > 0) bS[b] = atomicAdd(&curS[b], cS[b]);
        if (cD[b] > 0) bD[b] = atomicAdd(&curD[b], cD[b]);
    }
    __syncthreads();
    #pragma unroll
    for (int j = 0; j < EPT; ++j) {
        if (myd[j] >= 0) {
            int s = mys[j], d = myd[j];
            bsrc[bS[s >> RPB_SHIFT] + myrS[j]] = s;
            bpk[bD[d >> RPB_SHIFT] + myrD[j]] = ((d & (RPB - 1)) << SRC_BITS) | s;
        }
    }
}

// ---------------- merged per-bucket finalize (both graphs, both sides) ----------------
// blocks: [0,NB_UI) UI-dst, [NB_UI,2*NB_UI) UI-src,
//         [2*NB_UI, 2*NB_UI+NB_UU) UU-dst, rest UU-src.

__global__ __launch_bounds__(FBLK) void bucket_finalize_both_kernel(
    const int* __restrict__ ui_binned, const int* __restrict__ ui_binned_src,
    const int* __restrict__ uu_binned, const int* __restrict__ uu_binned_src,
    const int* __restrict__ bases,
    int* __restrict__ ui_row_ptr, float* __restrict__ ui_rsq_in,
    int* __restrict__ ui_col, float* __restrict__ ui_rsq_out,
    int* __restrict__ uu_row_ptr, float* __restrict__ uu_rsq_in,
    int* __restrict__ uu_col, float* __restrict__ uu_rsq_out) {
    __shared__ int deg[RPB];
    __shared__ int cur[RPB];
    __shared__ int wsum[FBLK / 64];
    __shared__ int carry;
    int bb = blockIdx.x;
    int t = threadIdx.x, lane = t & 63, wid = t >> 6;

    const int* binned = nullptr;
    const int* base = nullptr;
    int* row_ptr = nullptr;
    float* rsq_in = nullptr;
    int* col = nullptr;
    float* rsq_out = nullptr;
    int b = 0, nb = 0, n = 0;
    bool dstSide;
    if (bb < NB_UI) {
        dstSide = true; b = bb; nb = NB_UI; n = N_ALL;
        binned = ui_binned; base = bases;
        row_ptr = ui_row_ptr; rsq_in = ui_rsq_in; col = ui_col;
    } else if (bb < 2 * NB_UI) {
        dstSide = false; b = bb - NB_UI; nb = NB_UI; n = N_ALL;
        binned = ui_binned_src; base = bases + (MAX_NB + 1);
        rsq_out = ui_rsq_out;
    } else if (bb < 2 * NB_UI + NB_UU) {
        dstSide = true; b = bb - 2 * NB_UI; nb = NB_UU; n = N_USER;
        binned = uu_binned; base = bases + 2 * (MAX_NB + 1);
        row_ptr = uu_row_ptr; rsq_in = uu_rsq_in; col = uu_col;
    } else {
        dstSide = false; b = bb - 2 * NB_UI - NB_UU; nb = NB_UU; n = N_USER;
        binned = uu_binned_src; base = bases + 3 * (MAX_NB + 1);
        rsq_out = uu_rsq_out;
    }

    int row0 = b << RPB_SHIFT;
    int beg = base[b], end = base[b + 1];

    if (!dstSide) {
        for (int i = t; i < RPB; i += FBLK) deg[i] = 0;
        __syncthreads();
        for (int e = beg + t; e < end; e += FBLK)
            atomicAdd(&deg[binned[e] - row0], 1);
        __syncthreads();
        for (int i = t; i < RPB; i += FBLK)
            if (row0 + i < n)
                rsq_out[row0 + i] = 1.0f / sqrtf(fmaxf((float)deg[i], 1.0f));
        return;
    }

    int nrows = min(RPB, n - row0);
    for (int i = t; i < RPB; i += FBLK) deg[i] = 0;
    __syncthreads();

    for (int e = beg + t; e < end; e += FBLK)
        atomicAdd(&deg[binned[e] >> SRC_BITS], 1);

    if (t == 0) carry = 0;
    for (int c0 = 0; c0 < RPB; c0 += FBLK) {
        __syncthreads();
        int x = deg[c0 + t];
        int s = wave_incl_scan(x, lane);
        if (lane == 63) wsum[wid] = s;
        __syncthreads();
        int add = carry;
        for (int w = 0; w < wid; ++w) add += wsum[w];
        int excl = add + s - x;
        cur[c0 + t] = beg + excl;
        if (c0 + t < nrows) {
            row_ptr[row0 + c0 + t] = beg + excl;
            rsq_in[row0 + c0 + t] = 1.0f / sqrtf(fmaxf((float)x, 1.0f));
        }
        int total = 0;
        #pragma unroll
        for (int w = 0; w < FBLK / 64; ++w) total += wsum[w];
        __syncthreads();
        if (t == 0) carry = add + total;
    }
    __syncthreads();
    if (b == nb - 1 && t == 0) row_ptr[n] = end;
    __syncthreads();

    for (int e = beg + t; e < end; e += FBLK) {
        int p = binned[e];
        int pos = atomicAdd(&cur[p >> SRC_BITS], 1);
        col[pos] = p & SRC_MASK;
    }
}

// ---------------- plain GCN layer: gather -> emb_out only (no sum I/O) ----------------

__global__ void gcn_layer_plain_kernel(const int* __restrict__ row_ptr,
                                       const int* __restrict__ col,
                                       const bf16* __restrict__ emb_in,
                                       const float* __restrict__ rsq_in,
                                       const float* __restrict__ rsq_out,
                                       bf16* __restrict__ emb_out,
                                       int n) {
    int wave = blockIdx.x * (blockDim.x >> 6) + (threadIdx.x >> 6);
    int lane = threadIdx.x & 63;
    int q = lane & 7;
    int row = wave * 8 + (lane >> 3);
    bool act = row < n;
    int beg = 0, end = 0;
    if (act) { beg = row_ptr[row]; end = row_ptr[row + 1]; }
    float rin = act ? rsq_in[row] : 0.f;
    float ro  = act ? rsq_out[row] : 0.f;

    float acc[8];
    #pragma unroll
    for (int k = 0; k < 8; ++k) acc[k] = 0.f;

    const int4* __restrict__ embv = (const int4*)emb_in;

    int e = beg;
    for (; e + 4 <= end; e += 4) {
        int s0 = col[e];
        int s1 = col[e + 1];
        int s2 = col[e + 2];
        int s3 = col[e + 3];
        int4 w0 = embv[(size_t)s0 * 8 + q];
        int4 w1 = embv[(size_t)s1 * 8 + q];
        int4 w2 = embv[(size_t)s2 * 8 + q];
        int4 w3 = embv[(size_t)s3 * 8 + q];
        acc8(acc, w0);
        acc8(acc, w1);
        acc8(acc, w2);
        acc8(acc, w3);
    }
    for (; e < end; ++e) {
        int4 w0 = embv[(size_t)col[e] * 8 + q];
        acc8(acc, w0);
    }

    float vv[8];
    #pragma unroll
    for (int k = 0; k < 8; ++k) {
        float v = acc[k] * rin;
        vv[k] = (v > 0.f) ? v : 0.5f * v;   // LeakyReLU(0.5)
    }

    if (act) {
        size_t o = (size_t)row * D + (size_t)q * 8;
        union { i32x4 i4; bf16 h[8]; } pk;
        #pragma unroll
        for (int k = 0; k < 8; ++k) pk.h[k] = __float2bfloat16(vv[k] * ro);
        __builtin_nontemporal_store(pk.i4, (i32x4*)(emb_out + o));
    }
}

// ---------------- final GCN layer: own contribution + recomputed prior norms ----------------
// sum_out[row] = init[row] + n(prev1[row]) [+ n(prev2[row])] + v/||v||
// (norms of emb buffers equal norms of v since emb = v * rsq_out, scalar per row)

__global__ void gcn_layer_final_kernel(const int* __restrict__ row_ptr,
                                       const int* __restrict__ col,
                                       const bf16* __restrict__ emb_in,
                                       const float* __restrict__ rsq_in,
                                       const float* __restrict__ initA,
                                       const float* __restrict__ initB,
                                       long splitElems,
                                       const bf16* __restrict__ prev1,
                                       const bf16* __restrict__ prev2,
                                       float* __restrict__ sum_out,
                                       int n) {
    int wave = blockIdx.x * (blockDim.x >> 6) + (threadIdx.x >> 6);
    int lane = threadIdx.x & 63;
    int q = lane & 7;
    int row = wave * 8 + (lane >> 3);
    bool act = row < n;
    int beg = 0, end = 0;
    if (act) { beg = row_ptr[row]; end = row_ptr[row + 1]; }
    float rin = act ? rsq_in[row] : 0.f;
    size_t o = (size_t)row * D + (size_t)q * 8;

    // hoisted: init base (nt, streamed once)
    f32x4 i0 = {0.f, 0.f, 0.f, 0.f}, i1 = {0.f, 0.f, 0.f, 0.f};
    if (act) {
        const float* bsrc = ((size_t)row * D < (size_t)splitElems)
                                ? (initA + o) : (initB + (o - splitElems));
        const f32x4* sp = (const f32x4*)bsrc;
        i0 = __builtin_nontemporal_load(sp);
        i1 = __builtin_nontemporal_load(sp + 1);
    }
    // hoisted: prior emb rows
    float p1f[8], p2f[8];
    #pragma unroll
    for (int k = 0; k < 8; ++k) { p1f[k] = 0.f; p2f[k] = 0.f; }
    if (act) {
        size_t idx = (size_t)row * 8 + q;
        i32x4 p1;
        if (prev1 == emb_in) p1 = *((const i32x4*)prev1 + idx);       // gather table: keep cached
        else p1 = __builtin_nontemporal_load((const i32x4*)prev1 + idx);
        unpack8(p1, p1f);
        if (prev2) {
            i32x4 p2 = *((const i32x4*)prev2 + idx);
            unpack8(p2, p2f);
        }
    }

    float acc[8];
    #pragma unroll
    for (int k = 0; k < 8; ++k) acc[k] = 0.f;

    const int4* __restrict__ embv = (const int4*)emb_in;

    int e = beg;
    for (; e + 4 <= end; e += 4) {
        int s0 = col[e];
        int s1 = col[e + 1];
        int s2 = col[e + 2];
        int s3 = col[e + 3];
        int4 w0 = embv[(size_t)s0 * 8 + q];
        int4 w1 = embv[(size_t)s1 * 8 + q];
        int4 w2 = embv[(size_t)s2 * 8 + q];
        int4 w3 = embv[(size_t)s3 * 8 + q];
        acc8(acc, w0);
        acc8(acc, w1);
        acc8(acc, w2);
        acc8(acc, w3);
    }
    for (; e < end; ++e) {
        int4 w0 = embv[(size_t)col[e] * 8 + q];
        acc8(acc, w0);
    }

    float vv[8];
    #pragma unroll
    for (int k = 0; k < 8; ++k) {
        float v = acc[k] * rin;
        vv[k] = (v > 0.f) ? v : 0.5f * v;   // LeakyReLU(0.5)
    }
    float invO = groupnorm_inv(vv);
    float inv1 = groupnorm_inv(p1f);
    float inv2 = prev2 ? groupnorm_inv(p2f) : 0.f;

    if (act) {
        f32x4 o0, o1;
        o0.x = i0.x + p1f[0] * inv1 + p2f[0] * inv2 + vv[0] * invO;
        o0.y = i0.y + p1f[1] * inv1 + p2f[1] * inv2 + vv[1] * invO;
        o0.z = i0.z + p1f[2] * inv1 + p2f[2] * inv2 + vv[2] * invO;
        o0.w = i0.w + p1f[3] * inv1 + p2f[3] * inv2 + vv[3] * invO;
        o1.x = i1.x + p1f[4] * inv1 + p2f[4] * inv2 + vv[4] * invO;
        o1.y = i1.y + p1f[5] * inv1 + p2f[5] * inv2 + vv[5] * invO;
        o1.z = i1.z + p1f[6] * inv1 + p2f[6] * inv2 + vv[6] * invO;
        o1.w = i1.w + p1f[7] * inv1 + p2f[7] * inv2 + vv[7] * invO;
        f32x4* op = (f32x4*)(sum_out + o);
        __builtin_nontemporal_store(o0, op);
        __builtin_nontemporal_store(o1, op + 1);
    }
}

// ---------------- host side ----------------

extern "C" void kernel_launch(void* const* d_in, const int* in_sizes, int n_in,
                              void* d_out, int out_size, void* d_ws, size_t ws_size,
                              hipStream_t stream) {
    const float* user_emb = (const float*)d_in[0];
    const float* item_emb = (const float*)d_in[1];
    const int*   ui_src   = (const int*)d_in[2];
    const int*   ui_dst   = (const int*)d_in[3];
    const int*   uu_src   = (const int*)d_in[4];
    const int*   uu_dst   = (const int*)d_in[5];

    float* out    = (float*)d_out;
    float* ui_sum = out;                          // [N_ALL * D]
    float* uu_sum = out + (size_t)N_ALL * D;      // [N_USER * D]

    // ws layout
    char* wp = (char*)d_ws;
    bf16* embA = (bf16*)wp;        wp += (size_t)N_ALL * D * sizeof(bf16);   // 38.4 MB
    bf16* embB = (bf16*)wp;        wp += (size_t)N_ALL * D * sizeof(bf16);   // 38.4 MB
    int* ui_binned     = (int*)wp; wp += (size_t)E_UI * sizeof(int);         // 12.8 MB
    int* ui_binned_src = (int*)wp; wp += (size_t)E_UI * sizeof(int);         // 12.8 MB
    int* uu_binned     = (int*)wp; wp += (size_t)E_UU * sizeof(int);         // 6.4 MB
    int* uu_binned_src = (int*)wp; wp += (size_t)E_UU * sizeof(int);         // 6.4 MB
    int*   uu_col     = (int*)wp;   wp += (size_t)E_UU * sizeof(int);        // 6.4 MB
    int*   uu_row_ptr = (int*)wp;   wp += (size_t)(N_USER + 1) * sizeof(int);
    float* uu_rsq_out = (float*)wp; wp += (size_t)N_USER * sizeof(float);
    float* uu_rsq_in  = (float*)wp; wp += (size_t)N_USER * sizeof(float);
    int* bc    = (int*)wp; wp += 4 * (size_t)MAX_NB * sizeof(int);
    int* bases = (int*)wp; wp += 4 * (size_t)(MAX_NB + 1) * sizeof(int);
    int* curs  = (int*)wp; wp += 4 * (size_t)MAX_NB * sizeof(int);

    // UI CSR scratch in the uu_sum region of d_out (dead during UI phase; 16.4/25.6 MB)
    char* p = (char*)uu_sum;
    int*   ui_col     = (int*)p;   p += (size_t)E_UI * sizeof(int);
    int*   ui_row_ptr = (int*)p;   p += (size_t)(N_ALL + 1) * sizeof(int);
    float* ui_rsq_out = (float*)p; p += (size_t)N_ALL * sizeof(float);
    float* ui_rsq_in  = (float*)p; p += (size_t)N_ALL * sizeof(float);

    // ---------------- merged build (both graphs) ----------------
    (void)hipMemsetAsync(bc, 0, 4 * (size_t)MAX_NB * sizeof(int), stream);
    bucket_hist_both_kernel<<<H_UI + H_UU, BLK, 0, stream>>>(
        ui_src, ui_dst, uu_src, uu_dst, bc);
    scan4_kernel<<<1, BLK, 0, stream>>>(bc, bases, curs);
    bin_scatter2_both_kernel<<<T_UI + T_UU, SBLK, 0, stream>>>(
        ui_src, ui_dst, uu_src, uu_dst, curs,
        ui_binned_src, ui_binned, uu_binned_src, uu_binned);
    bucket_finalize_both_kernel<<<2 * NB_UI + 2 * NB_UU, FBLK, 0, stream>>>(
        ui_binned, ui_binned_src, uu_binned, uu_binned_src, bases,
        ui_row_ptr, ui_rsq_in, ui_col, ui_rsq_out,
        uu_row_ptr, uu_rsq_in, uu_col, uu_rsq_out);

    const int ROWS_PER_BLK = (BLK / 64) * 8;  // 32

    // ---------------- user-item graph ----------------
    {
        size_t tot = (size_t)N_ALL * D;
        init_ui_kernel<<<cdiv((int)tot, BLK), BLK, 0, stream>>>(
            user_emb, item_emb, ui_rsq_out, embA);

        int grid = cdiv(N_ALL, ROWS_PER_BLK);
        // l0: A -> B (emb_1)
        gcn_layer_plain_kernel<<<grid, BLK, 0, stream>>>(
            ui_row_ptr, ui_col, embA, ui_rsq_in, ui_rsq_out, embB, N_ALL);
        // l1: B -> A (emb_2)
        gcn_layer_plain_kernel<<<grid, BLK, 0, stream>>>(
            ui_row_ptr, ui_col, embB, ui_rsq_in, ui_rsq_out, embA, N_ALL);
        // l2: gather A, combine init + n(emb_1=B) + n(emb_2=A) + own -> ui_sum
        gcn_layer_final_kernel<<<grid, BLK, 0, stream>>>(
            ui_row_ptr, ui_col, embA, ui_rsq_in,
            user_emb, item_emb, (long)N_USER * D,
            embB, embA, ui_sum, N_ALL);
    }

    // ---------------- user-user graph ----------------
    {
        size_t tot = (size_t)N_USER * D;
        init_uu_kernel<<<cdiv((int)tot, BLK), BLK, 0, stream>>>(
            user_emb, uu_rsq_out, embA);

        int grid = cdiv(N_USER, ROWS_PER_BLK);
        // l0: A -> B (emb_1)
        gcn_layer_plain_kernel<<<grid, BLK, 0, stream>>>(
            uu_row_ptr, uu_col, embA, uu_rsq_in, uu_rsq_out, embB, N_USER);
        // l1: gather B, combine init(ue) + n(emb_1=B) + own -> uu_sum
        gcn_layer_final_kernel<<<grid, BLK, 0, stream>>>(
            uu_row_ptr, uu_col, embB, uu_rsq_in,
            user_emb, nullptr, (long)N_USER * D,
            embB, nullptr, uu_sum, N_USER);
    }
}